// Round 1
// baseline (893.054 us; speedup 1.0000x reference)
//
#include <hip/hip_runtime.h>

#define NN 100000
#define EE 1000000
#define ET (EE + NN)
#define HC 128

// ---- ordered-uint encoding for float atomicMax ----
__device__ __forceinline__ unsigned fenc(float f) {
    unsigned u = __float_as_uint(f);
    return (u & 0x80000000u) ? ~u : (u | 0x80000000u);
}
__device__ __forceinline__ float fdec(unsigned u) {
    return __uint_as_float((u & 0x80000000u) ? (u & 0x7fffffffu) : ~u);
}

// ---- K1: h = x @ W  (+ fused attention dot products) ----
__global__ __launch_bounds__(256) void k_gemm(
    const float* __restrict__ x, const float* __restrict__ W,
    const float* __restrict__ atts, const float* __restrict__ attd,
    float* __restrict__ h, float* __restrict__ asrc, float* __restrict__ adst)
{
    __shared__ float Wl[HC * HC];   // 64 KB, 2 blocks/CU
    for (int i = threadIdx.x * 4; i < HC * HC; i += 256 * 4)
        *(float4*)&Wl[i] = *(const float4*)&W[i];
    __syncthreads();

    const int wv = threadIdx.x >> 6, lane = threadIdx.x & 63;
    const float as0 = atts[lane], as1 = atts[64 + lane];
    const float ad0 = attd[lane], ad1 = attd[64 + lane];

    for (int row = blockIdx.x * 4 + wv; row < NN; row += gridDim.x * 4) {
        const float* xr = x + (size_t)row * HC;
        float acc0 = 0.f, acc1 = 0.f;
        #pragma unroll 4
        for (int k4 = 0; k4 < HC / 4; ++k4) {
            const float4 xv = *(const float4*)(xr + k4 * 4);
            const int b = k4 * 4 * HC + lane;
            acc0 = fmaf(xv.x, Wl[b],            acc0);
            acc1 = fmaf(xv.x, Wl[b + 64],       acc1);
            acc0 = fmaf(xv.y, Wl[b + HC],       acc0);
            acc1 = fmaf(xv.y, Wl[b + HC + 64],  acc1);
            acc0 = fmaf(xv.z, Wl[b + 2*HC],     acc0);
            acc1 = fmaf(xv.z, Wl[b + 2*HC + 64],acc1);
            acc0 = fmaf(xv.w, Wl[b + 3*HC],     acc0);
            acc1 = fmaf(xv.w, Wl[b + 3*HC + 64],acc1);
        }
        h[(size_t)row * HC + lane]      = acc0;   // head0 channel `lane`
        h[(size_t)row * HC + 64 + lane] = acc1;   // head1 channel `lane`

        float p0 = acc0 * as0, p1 = acc1 * as1;
        float q0 = acc0 * ad0, q1 = acc1 * ad1;
        for (int m = 32; m; m >>= 1) {
            p0 += __shfl_xor(p0, m); p1 += __shfl_xor(p1, m);
            q0 += __shfl_xor(q0, m); q1 += __shfl_xor(q1, m);
        }
        if (!lane) {
            asrc[row * 2] = p0; asrc[row * 2 + 1] = p1;
            adst[row * 2] = q0; adst[row * 2 + 1] = q1;
        }
    }
}

__device__ __forceinline__ void edge_sd(const int* __restrict__ ei, int t, int& s, int& d) {
    if (t < EE) { s = ei[t]; d = ei[EE + t]; }
    else        { s = t - EE; d = t - EE; }           // self-loops appended
}

__device__ __forceinline__ void edge_e(const float* __restrict__ asrc,
                                       const float* __restrict__ adst,
                                       int s, int d, float& e0, float& e1) {
    float2 av = *(const float2*)&asrc[s * 2];
    float2 bv = *(const float2*)&adst[d * 2];
    e0 = av.x + bv.x;  e1 = av.y + bv.y;
    e0 = e0 > 0.f ? e0 : 0.2f * e0;                   // leaky_relu(0.2)
    e1 = e1 > 0.f ? e1 : 0.2f * e1;
}

// ---- K2: segment max over dst (atomicMax on ordered uints) ----
__global__ __launch_bounds__(256) void k_edge_max(
    const int* __restrict__ ei, const float* __restrict__ asrc,
    const float* __restrict__ adst, unsigned* __restrict__ menc)
{
    int t = blockIdx.x * 256 + threadIdx.x;
    if (t >= ET) return;
    int s, d; edge_sd(ei, t, s, d);
    float e0, e1; edge_e(asrc, adst, s, d, e0, e1);
    atomicMax(&menc[d * 2],     fenc(e0));
    atomicMax(&menc[d * 2 + 1], fenc(e1));
}

// ---- K3: p = exp(e - m), segment sum ----
__global__ __launch_bounds__(256) void k_edge_exp(
    const int* __restrict__ ei, const float* __restrict__ asrc,
    const float* __restrict__ adst, const unsigned* __restrict__ menc,
    float* __restrict__ ssum, float* __restrict__ p)
{
    int t = blockIdx.x * 256 + threadIdx.x;
    if (t >= ET) return;
    int s, d; edge_sd(ei, t, s, d);
    float e0, e1; edge_e(asrc, adst, s, d, e0, e1);
    float p0 = __expf(e0 - fdec(menc[d * 2]));
    float p1 = __expf(e1 - fdec(menc[d * 2 + 1]));
    p[t * 2] = p0; p[t * 2 + 1] = p1;
    atomicAdd(&ssum[d * 2],     p0);
    atomicAdd(&ssum[d * 2 + 1], p1);
}

// ---- K4: out[dst] += alpha * h[src]  (64 lanes per edge, 2 ch/lane) ----
__global__ __launch_bounds__(256) void k_scatter(
    const int* __restrict__ ei, const float* __restrict__ h,
    const float* __restrict__ p, const float* __restrict__ ssum,
    float* __restrict__ out)
{
    long long g = (long long)blockIdx.x * 256 + threadIdx.x;
    int t = (int)(g >> 6), lane = (int)(g & 63);
    if (t >= ET) return;
    int s, d; edge_sd(ei, t, s, d);
    float a0 = p[t * 2]     / ssum[d * 2];
    float a1 = p[t * 2 + 1] / ssum[d * 2 + 1];
    atomicAdd(&out[(size_t)d * HC + lane],      a0 * h[(size_t)s * HC + lane]);
    atomicAdd(&out[(size_t)d * HC + 64 + lane], a1 * h[(size_t)s * HC + 64 + lane]);
}

// ---- K5: bias + ReLU in place, per-channel partial sums for BN ----
__global__ __launch_bounds__(128) void k_relu_stats(
    float* __restrict__ out, const float* __restrict__ bias,
    float* __restrict__ gsum, float* __restrict__ gsq)
{
    int c = threadIdx.x;
    float b = bias[c], sum = 0.f, sq = 0.f;
    for (int r = blockIdx.x; r < NN; r += gridDim.x) {
        float v = out[(size_t)r * HC + c] + b;
        v = v > 0.f ? v : 0.f;
        out[(size_t)r * HC + c] = v;
        sum += v; sq += v * v;
    }
    atomicAdd(&gsum[c], sum);
    atomicAdd(&gsq[c], sq);
}

// ---- K6: BN scale/shift from batch stats ----
__global__ void k_bnparam(const float* __restrict__ gsum, const float* __restrict__ gsq,
                          const float* __restrict__ gamma, const float* __restrict__ beta,
                          float* __restrict__ scsh)
{
    int c = threadIdx.x;  // 128
    float mean = gsum[c] * (1.f / NN);
    float var  = gsq[c] * (1.f / NN) - mean * mean;
    float sc   = gamma[c] * rsqrtf(var + 1e-5f);
    scsh[c]        = sc;
    scsh[128 + c]  = beta[c] - mean * sc;
}

// ---- K7: affine apply in place (float4) ----
__global__ __launch_bounds__(256) void k_apply(float* __restrict__ out,
                                               const float* __restrict__ scsh)
{
    size_t i = (size_t)blockIdx.x * 256 + threadIdx.x;
    if (i * 4 >= (size_t)NN * HC) return;
    float4 v = ((float4*)out)[i];
    int c = (int)((i * 4) & (HC - 1));
    v.x = v.x * scsh[c]     + scsh[128 + c];
    v.y = v.y * scsh[c + 1] + scsh[128 + c + 1];
    v.z = v.z * scsh[c + 2] + scsh[128 + c + 2];
    v.w = v.w * scsh[c + 3] + scsh[128 + c + 3];
    ((float4*)out)[i] = v;
}

extern "C" void kernel_launch(void* const* d_in, const int* in_sizes, int n_in,
                              void* d_out, int out_size, void* d_ws, size_t ws_size,
                              hipStream_t stream) {
    const float* x     = (const float*)d_in[0];
    const int*   ei    = (const int*)  d_in[1];
    const float* W     = (const float*)d_in[2];
    const float* atts  = (const float*)d_in[3];
    const float* attd  = (const float*)d_in[4];
    const float* bias  = (const float*)d_in[5];
    const float* gamma = (const float*)d_in[6];
    const float* beta  = (const float*)d_in[7];
    float* out = (float*)d_out;
    float* ws  = (float*)d_ws;

    // ws layout (floats)
    float*    h    = ws;                         // 12,800,000
    float*    asrc = ws + 12800000;              //    200,000
    float*    adst = ws + 13000000;              //    200,000
    unsigned* menc = (unsigned*)(ws + 13200000); //    200,000  \  contiguous
    float*    ssum = ws + 13400000;              //    200,000   } zero region
    float*    gsum = ws + 13600000;              //        128   }
    float*    gsq  = ws + 13600128;              //        128  /
    float*    scsh = ws + 13600256;              //        256
    float*    p    = ws + 13600512;              //  2,200,000   (total ~63.2 MB)

    hipMemsetAsync(out,  0, (size_t)NN * HC * sizeof(float), stream);
    hipMemsetAsync(menc, 0, (size_t)400256 * sizeof(float), stream);

    k_gemm      <<<2048, 256, 0, stream>>>(x, W, atts, attd, h, asrc, adst);
    k_edge_max  <<<(ET + 255) / 256, 256, 0, stream>>>(ei, asrc, adst, menc);
    k_edge_exp  <<<(ET + 255) / 256, 256, 0, stream>>>(ei, asrc, adst, menc, ssum, p);
    k_scatter   <<<ET / 4, 256, 0, stream>>>(ei, h, p, ssum, out);
    k_relu_stats<<<2048, 128, 0, stream>>>(out, bias, gsum, gsq);
    k_bnparam   <<<1, 128, 0, stream>>>(gsum, gsq, gamma, beta, scsh);
    k_apply     <<<(NN * HC / 4 + 255) / 256, 256, 0, stream>>>(out, scsh);
}